// Round 6
// baseline (91.379 us; speedup 1.0000x reference)
//
#include <hip/hip_runtime.h>
#include <math.h>

typedef _Float16 f16;
typedef __attribute__((ext_vector_type(8))) _Float16 f16x8;
typedef __attribute__((ext_vector_type(16))) float f32x16;

// sat (128,4,64,16) f32, grd (128,4,64,16) f32
// out (f32): sat 524288 | grd 524288 | distance[g][s] 16384 | orien[s][g] 16384
#define DIST_OFF  1048576
#define ORI_OFF   1064960
#define SATP_STR  72          // f16 elems per satP row (144 B, 16B-multiple)
#define RTS       68          // red tile j-stride (16B-aligned, swizzled banks)

#define MFMA(a,b,c) __builtin_amdgcn_mfma_f32_32x32x16_f16((a),(b),(c),0,0,0)
// bank swizzle: flip j bit4 by g bit3 -> b128 conflicts drop to 2-way (free)
#define RIDX(g, j0) ((g) * RTS + ((j0) ^ ((((g) >> 3) & 1) << 4)))

// ---- prep: grd -> frag-ready grdF[kb][g][e] hi/lo (k = dw*64 + h*16 + c) ----
__global__ __launch_bounds__(256) void prep_k(const float* __restrict__ grd,
                                              f16* __restrict__ gHi, f16* __restrict__ gLo) {
    __shared__ f16 tH[8192], tL[8192];          // [kb_l 64][g_l 16][e 8]
    const int b = blockIdx.x;
    const int tid = threadIdx.x;
    const int g0 = (b & 7) * 16;
    const int kq = b >> 3;                      // k-range [kq*512, kq*512+512)
    #pragma unroll
    for (int i = 0; i < 32; ++i) {
        int flat = i * 256 + tid;               // [g_l 16][h 4][j 128], coalesced reads
        int g_l = flat >> 9;
        int r   = flat & 511;
        int h   = r >> 7;
        int j   = r & 127;                      // dw_l = j>>4, c = j&15
        float v = grd[(((g0 + g_l) * 4 + h) * 64 + kq * 8) * 16 + j];
        int k_l = (j >> 4) * 64 + h * 16 + (j & 15);
        f16 hv = (f16)v;
        int a = (k_l >> 3) * 128 + g_l * 8 + (k_l & 7);
        tH[a] = hv;
        tL[a] = (f16)(v - (float)hv);
    }
    __syncthreads();
    #pragma unroll
    for (int i = 0; i < 4; ++i) {
        int f = i * 256 + tid;                  // frag: kb_l = f>>4, g_l = f&15
        int dst = (kq * 64 + (f >> 4)) * 128 + g0 + (f & 15);
        ((f16x8*)gHi)[dst] = *(const f16x8*)(tH + f * 8);
        ((f16x8*)gLo)[dst] = *(const f16x8*)(tL + f * 8);
    }
}

// ---- corr: block=(s, g-half64), 16 waves = 16-way K split, wave tile 64j x 64g ----
__global__ __launch_bounds__(1024, 4) void corr_k(const float* __restrict__ sat,
                                                  const f16* __restrict__ gHi,
                                                  const f16* __restrict__ gLo,
                                                  float* __restrict__ out) {
    __shared__ __align__(16) unsigned char smem[69632];  // satP 36.6KB | red 4x64x68 f32
    __shared__ float wred[16];
    __shared__ float rnormS;
    f16* sH = (f16*)smem;                 // [w' 0..126][hc 0..63], stride 72
    f16* sL = sH + 127 * SATP_STR;
    float* red = (float*)smem;

    const int tid = threadIdx.x;
    const int s  = blockIdx.x >> 1;
    const int gh = blockIdx.x & 1;
    const int wave = tid >> 6, lane = tid & 63;
    const int m = lane & 31, half = lane >> 5;

    // ---- stage satP hi/lo (doubled along w) + ||sat[s]||^2 ----
    const float* satS = sat + s * 4096;
    float ssq = 0.f;
    #pragma unroll
    for (int r = 0; r < 4; ++r) {
        int idx = r * 1024 + tid;
        float v = satS[idx];
        int h = idx >> 10, w = (idx >> 4) & 63, c = idx & 15;
        int col = h * 16 + c;
        f16 hv = (f16)v, lv = (f16)(v - (float)hv);
        sH[w * SATP_STR + col] = hv;
        sL[w * SATP_STR + col] = lv;
        if (w < 63) { sH[(w + 64) * SATP_STR + col] = hv; sL[(w + 64) * SATP_STR + col] = lv; }
        ssq += v * v;
    }
    #pragma unroll
    for (int off = 32; off > 0; off >>= 1) ssq += __shfl_down(ssq, off, 64);
    if (lane == 0) wred[wave] = ssq;
    __syncthreads();
    if (tid == 0) {
        float t = 0.f;
        #pragma unroll
        for (int i = 0; i < 16; ++i) t += wred[i];
        rnormS = 1.f / fmaxf(sqrtf(t), 1e-12f);
    }

    // ---- K-loop: wave handles 16 k-tiles of 16; merged accumulators ----
    const f16* A0h = sH + m * SATP_STR + half * 8;
    const f16* A0l = sL + m * SATP_STR + half * 8;
    const f16x8* BHp = (const f16x8*)gHi;
    const f16x8* BLp = (const f16x8*)gLo;
    const int ggBase = half * 128 + gh * 64 + m;

    f32x16 acc[2][2];
    #pragma unroll
    for (int jt = 0; jt < 2; ++jt)
        #pragma unroll
        for (int gt = 0; gt < 2; ++gt)
            #pragma unroll
            for (int r = 0; r < 16; ++r) acc[jt][gt][r] = 0.f;

    const int t0 = wave * 16;
    #pragma unroll 4
    for (int t = t0; t < t0 + 16; ++t) {
        int ao = (t >> 2) * SATP_STR + (t & 3) * 16;
        f16x8 ah0 = *(const f16x8*)(A0h + ao);
        f16x8 ah1 = *(const f16x8*)(A0h + ao + 32 * SATP_STR);
        f16x8 al0 = *(const f16x8*)(A0l + ao);
        f16x8 al1 = *(const f16x8*)(A0l + ao + 32 * SATP_STR);
        int bu = t * 256 + ggBase;
        f16x8 bh0 = BHp[bu], bh1 = BHp[bu + 32];
        f16x8 bl0 = BLp[bu], bl1 = BLp[bu + 32];
        acc[0][0] = MFMA(ah0, bh0, acc[0][0]);
        acc[0][1] = MFMA(ah0, bh1, acc[0][1]);
        acc[1][0] = MFMA(ah1, bh0, acc[1][0]);
        acc[1][1] = MFMA(ah1, bh1, acc[1][1]);
        acc[0][0] = MFMA(ah0, bl0, acc[0][0]);
        acc[0][1] = MFMA(ah0, bl1, acc[0][1]);
        acc[1][0] = MFMA(ah1, bl0, acc[1][0]);
        acc[1][1] = MFMA(ah1, bl1, acc[1][1]);
        acc[0][0] = MFMA(al0, bh0, acc[0][0]);
        acc[0][1] = MFMA(al0, bh1, acc[0][1]);
        acc[1][0] = MFMA(al1, bh0, acc[1][0]);
        acc[1][1] = MFMA(al1, bh1, acc[1][1]);
    }

#define WTILE(T) { float* tp = red + (T) * 4352; \
    _Pragma("unroll") for (int jt = 0; jt < 2; ++jt) \
    _Pragma("unroll") for (int gt = 0; gt < 2; ++gt) { \
        int g = gt * 32 + m; \
        _Pragma("unroll") for (int q = 0; q < 4; ++q) { \
            int j0 = jt * 32 + 8 * q + 4 * half; \
            float4 v = { acc[jt][gt][4*q], acc[jt][gt][4*q+1], acc[jt][gt][4*q+2], acc[jt][gt][4*q+3] }; \
            *(float4*)(tp + RIDX(g, j0)) = v; } } }

#define ATILE(T) { const float* tp = red + (T) * 4352; \
    _Pragma("unroll") for (int jt = 0; jt < 2; ++jt) \
    _Pragma("unroll") for (int gt = 0; gt < 2; ++gt) { \
        int g = gt * 32 + m; \
        _Pragma("unroll") for (int q = 0; q < 4; ++q) { \
            int j0 = jt * 32 + 8 * q + 4 * half; \
            float4 v = *(const float4*)(tp + RIDX(g, j0)); \
            acc[jt][gt][4*q] += v.x; acc[jt][gt][4*q+1] += v.y; \
            acc[jt][gt][4*q+2] += v.z; acc[jt][gt][4*q+3] += v.w; } } }

    // ---- tree reduce: 16 partials -> wave 0 (4-tile buffer reused; satP dead) ----
    __syncthreads();
    if (wave >= 8 && wave < 12) WTILE(wave - 8)
    __syncthreads();
    if (wave < 4) ATILE(wave)
    __syncthreads();
    if (wave >= 12) WTILE(wave - 12)
    __syncthreads();
    if (wave >= 4 && wave < 8) ATILE(wave - 4)
    __syncthreads();
    if (wave >= 4 && wave < 8) WTILE(wave - 4)
    __syncthreads();
    if (wave < 4) ATILE(wave)
    __syncthreads();
    if (wave == 2 || wave == 3) WTILE(wave - 2)
    __syncthreads();
    if (wave < 2) ATILE(wave)
    __syncthreads();
    if (wave == 1) WTILE(0)
    __syncthreads();

    // ---- wave 0: final add + in-register argmax (first occurrence) ----
    if (wave == 0) {
        ATILE(0)
        #pragma unroll
        for (int gt = 0; gt < 2; ++gt) {
            float best = -1e30f;
            int bj = 0;
            #pragma unroll
            for (int jt = 0; jt < 2; ++jt)
                #pragma unroll
                for (int q = 0; q < 4; ++q)
                    #pragma unroll
                    for (int i = 0; i < 4; ++i) {       // ascending j within this lane
                        int j = jt * 32 + 8 * q + 4 * half + i;
                        float v = acc[jt][gt][4 * q + i];
                        if (v > best) { best = v; bj = j; }
                    }
            float ob = __shfl_xor(best, 32, 64);
            int  obj = __shfl_xor(bj, 32, 64);
            if (ob > best || (ob == best && obj < bj)) { best = ob; bj = obj; }
            if ((half == 0) == (gt == 0)) {             // one writer per g
                int g = gh * 64 + gt * 32 + m;
                float dot = best * rnormS;
                out[DIST_OFF + g * 128 + s] = 2.f - 2.f * dot;
                out[ORI_OFF + s * 128 + g]  = (float)bj;
            }
        }
    }
}

// Passthrough copies — runs LAST, overwrites the grdF staging region in d_out
__global__ void copy_k(const float4* __restrict__ a, const float4* __restrict__ b,
                       float4* __restrict__ out) {
    int i = blockIdx.x * 256 + threadIdx.x;
    out[i] = a[i];
    out[131072 + i] = b[i];
}

extern "C" void kernel_launch(void* const* d_in, const int* in_sizes, int n_in,
                              void* d_out, int out_size, void* d_ws, size_t ws_size,
                              hipStream_t stream) {
    const float* sat = (const float*)d_in[0];
    const float* grd = (const float*)d_in[1];
    float* out = (float*)d_out;

    // d_ws deliberately unused: its 268 MB 0xAA re-poison fill was landing in the
    // timed window. grdF hi/lo is staged in d_out's passthrough region instead.
    f16* gHi = (f16*)out;                 // floats [0, 262144)
    f16* gLo = (f16*)(out + 262144);      // floats [262144, 524288)

    prep_k<<<64, 256, 0, stream>>>(grd, gHi, gLo);
    corr_k<<<256, 1024, 0, stream>>>(sat, gHi, gLo, out);
    copy_k<<<512, 256, 0, stream>>>((const float4*)sat, (const float4*)grd, (float4*)out);
}

// Round 7
// 88.110 us; speedup vs baseline: 1.0371x; 1.0371x over previous
//
#include <hip/hip_runtime.h>
#include <math.h>

typedef _Float16 f16;
typedef __attribute__((ext_vector_type(8))) _Float16 f16x8;
typedef __attribute__((ext_vector_type(16))) float f32x16;

// sat (128,4,64,16) f32, grd (128,4,64,16) f32
// out (f32): sat 524288 | grd 524288 | distance[g][s] 16384 | orien[s][g] 16384
#define DIST_OFF  1048576
#define ORI_OFF   1064960
#define SATP_STR  72          // f16 elems per satP row (144 B, 16B-multiple)
#define RSTR      66          // red j-stride: bank = 2g%32 -> 2-way (free), 8B aligned

#define MFMA(a,b,c) __builtin_amdgcn_mfma_f32_32x32x16_f16((a),(b),(c),0,0,0)

// ---- prep: grd -> frag-ready grdF[kb][g][e] hi/lo (k = dw*64 + h*16 + c) ----
__global__ __launch_bounds__(256) void prep_k(const float* __restrict__ grd,
                                              f16* __restrict__ gHi, f16* __restrict__ gLo) {
    __shared__ f16 tH[8192], tL[8192];          // [kb_l 64][g_l 16][e 8]
    const int b = blockIdx.x;
    const int tid = threadIdx.x;
    const int g0 = (b & 7) * 16;
    const int kq = b >> 3;                      // k-range [kq*512, kq*512+512)
    #pragma unroll
    for (int i = 0; i < 32; ++i) {
        int flat = i * 256 + tid;               // [g_l 16][h 4][j 128], coalesced reads
        int g_l = flat >> 9;
        int r   = flat & 511;
        int h   = r >> 7;
        int j   = r & 127;                      // dw_l = j>>4, c = j&15
        float v = grd[(((g0 + g_l) * 4 + h) * 64 + kq * 8) * 16 + j];
        int k_l = (j >> 4) * 64 + h * 16 + (j & 15);
        f16 hv = (f16)v;
        int a = (k_l >> 3) * 128 + g_l * 8 + (k_l & 7);
        tH[a] = hv;
        tL[a] = (f16)(v - (float)hv);
    }
    __syncthreads();
    #pragma unroll
    for (int i = 0; i < 4; ++i) {
        int f = i * 256 + tid;                  // frag: kb_l = f>>4, g_l = f&15
        int dst = (kq * 64 + (f >> 4)) * 128 + g0 + (f & 15);
        ((f16x8*)gHi)[dst] = *(const f16x8*)(tH + f * 8);
        ((f16x8*)gLo)[dst] = *(const f16x8*)(tL + f * 8);
    }
}

// ---- corr: block=(s, gh), 16 waves = 16-way K split (ring-staggered), 64j x 64g ----
__global__ __launch_bounds__(1024, 4) void corr_k(const float* __restrict__ sat,
                                                  const f16* __restrict__ gHi,
                                                  const f16* __restrict__ gLo,
                                                  float* __restrict__ out,
                                                  const float4* __restrict__ satIn,
                                                  const float4* __restrict__ grdIn,
                                                  int fuse) {
    __shared__ __align__(16) unsigned char smem[135168];  // satP 36.6KB | red 8x64x66 f32
    __shared__ float wred[16];
    __shared__ float rnormS;
    f16* sH = (f16*)smem;                 // [w' 0..126][hc 0..63], stride 72
    f16* sL = sH + 127 * SATP_STR;
    float* red = (float*)smem;            // [kh 8][g 64][j stride 66]

    const int tid = threadIdx.x;
    const int s  = blockIdx.x >> 1;
    const int gh = blockIdx.x & 1;
    const int wave = tid >> 6, lane = tid & 63;
    const int m = lane & 31, half = lane >> 5;

    // ---- fused passthrough copies (overlap with staging; grdF lives in d_ws) ----
    if (fuse && tid < 512) {
        float4* o4 = (float4*)out;
        int i = blockIdx.x * 512 + tid;   // 0..131071
        o4[i] = satIn[i];
        o4[131072 + i] = grdIn[i];
    }

    // ---- stage satP hi/lo (doubled along w) + ||sat[s]||^2 ----
    const float* satS = sat + s * 4096;
    float ssq = 0.f;
    #pragma unroll
    for (int r = 0; r < 4; ++r) {
        int idx = r * 1024 + tid;
        float v = satS[idx];
        int h = idx >> 10, w = (idx >> 4) & 63, c = idx & 15;
        int col = h * 16 + c;
        f16 hv = (f16)v, lv = (f16)(v - (float)hv);
        sH[w * SATP_STR + col] = hv;
        sL[w * SATP_STR + col] = lv;
        if (w < 63) { sH[(w + 64) * SATP_STR + col] = hv; sL[(w + 64) * SATP_STR + col] = lv; }
        ssq += v * v;
    }
    #pragma unroll
    for (int off = 32; off > 0; off >>= 1) ssq += __shfl_down(ssq, off, 64);
    if (lane == 0) wred[wave] = ssq;
    __syncthreads();
    if (tid == 0) {
        float t = 0.f;
        #pragma unroll
        for (int i = 0; i < 16; ++i) t += wred[i];
        rnormS = 1.f / fmaxf(sqrtf(t), 1e-12f);
    }

    // ---- K-loop: wave owns 16 k-tiles, walked as a ring with per-wave stagger ----
    const f16* Ah = sH + m * SATP_STR + half * 8;
    const f16* Al = sL + m * SATP_STR + half * 8;
    const f16x8* BH = (const f16x8*)gHi + half * 128 + gh * 64 + m;
    const f16x8* BL = (const f16x8*)gLo + half * 128 + gh * 64 + m;

    f32x16 acc[2][2];
    #pragma unroll
    for (int jt = 0; jt < 2; ++jt)
        #pragma unroll
        for (int gt = 0; gt < 2; ++gt)
            #pragma unroll
            for (int r = 0; r < 16; ++r) acc[jt][gt][r] = 0.f;

    const int t0 = wave * 16;
    const int rot = (wave & 3) * 4;       // de-convoy: stagger load bursts across waves
    #pragma unroll 4
    for (int i = 0; i < 16; ++i) {
        int t = t0 + ((i + rot) & 15);
        int ao = (t >> 2) * SATP_STR + (t & 3) * 16;
        f16x8 ah0 = *(const f16x8*)(Ah + ao);
        f16x8 ah1 = *(const f16x8*)(Ah + ao + 32 * SATP_STR);
        f16x8 al0 = *(const f16x8*)(Al + ao);
        f16x8 al1 = *(const f16x8*)(Al + ao + 32 * SATP_STR);
        int bu = t * 256;
        f16x8 bh0 = BH[bu], bh1 = BH[bu + 32];
        f16x8 bl0 = BL[bu], bl1 = BL[bu + 32];
        acc[0][0] = MFMA(ah0, bh0, acc[0][0]);
        acc[0][1] = MFMA(ah0, bh1, acc[0][1]);
        acc[1][0] = MFMA(ah1, bh0, acc[1][0]);
        acc[1][1] = MFMA(ah1, bh1, acc[1][1]);
        acc[0][0] = MFMA(ah0, bl0, acc[0][0]);
        acc[0][1] = MFMA(ah0, bl1, acc[0][1]);
        acc[1][0] = MFMA(ah1, bl0, acc[1][0]);
        acc[1][1] = MFMA(ah1, bl1, acc[1][1]);
        acc[0][0] = MFMA(al0, bh0, acc[0][0]);
        acc[0][1] = MFMA(al0, bh1, acc[0][1]);
        acc[1][0] = MFMA(al1, bh0, acc[1][0]);
        acc[1][1] = MFMA(al1, bh1, acc[1][1]);
    }

    // ---- flat reduce: 16 partials -> 8 slots -> sum; 4 barriers total ----
    __syncthreads();                       // satP dead; red reuses smem
#define PUT(rp, op) { \
    _Pragma("unroll") for (int jt = 0; jt < 2; ++jt) \
    _Pragma("unroll") for (int gt = 0; gt < 2; ++gt) { \
        float* row = (rp) + (gt * 32 + m) * RSTR + jt * 32 + half * 4; \
        _Pragma("unroll") for (int q = 0; q < 4; ++q) { \
            float2 u = { acc[jt][gt][4*q], acc[jt][gt][4*q+1] }; \
            float2 v = { acc[jt][gt][4*q+2], acc[jt][gt][4*q+3] }; \
            op(row + q * 8, u, v); } } }
#define OPW(p, u, v)  { *(float2*)(p) = u; *(float2*)((p) + 2) = v; }
#define OPA(p, u, v)  { float2 a = *(float2*)(p), b = *(float2*)((p) + 2); \
                        a.x += u.x; a.y += u.y; b.x += v.x; b.y += v.y; \
                        *(float2*)(p) = a; *(float2*)((p) + 2) = b; }

    if (wave >= 8) PUT(red + (wave - 8) * 4224, OPW)
    __syncthreads();
    if (wave < 8)  PUT(red + wave * 4224, OPA)
    __syncthreads();
    {
        int g = tid >> 4, q4 = (tid & 15) * 4;
        int base = g * RSTR + q4;
        float2 u = {0.f, 0.f}, v = {0.f, 0.f};
        #pragma unroll
        for (int kh = 0; kh < 8; ++kh) {
            float2 a = *(const float2*)(red + kh * 4224 + base);
            float2 b = *(const float2*)(red + kh * 4224 + base + 2);
            u.x += a.x; u.y += a.y; v.x += b.x; v.y += b.y;
        }
        *(float2*)(red + base) = u;       // own cells only: race-free
        *(float2*)(red + base + 2) = v;
    }
    __syncthreads();

    // ---- argmax over j (first occurrence), distance + orien ----
    if (tid < 64) {
        int g = tid;
        const float* row = red + g * RSTR;
        float best = row[0];
        int bj = 0;
        for (int j = 1; j < 64; ++j) {
            float v = row[j];
            if (v > best) { best = v; bj = j; }
        }
        float dot = best * rnormS;
        int gg = gh * 64 + g;
        out[DIST_OFF + gg * 128 + s] = 2.f - 2.f * dot;
        out[ORI_OFF + s * 128 + gg]  = (float)bj;
    }
}

// Fallback passthrough copies (when grdF was staged inside d_out's sat region)
__global__ void copy_k(const float4* __restrict__ a, const float4* __restrict__ b,
                       float4* __restrict__ out) {
    int i = blockIdx.x * 256 + threadIdx.x;
    out[i] = a[i];
    out[131072 + i] = b[i];
}

extern "C" void kernel_launch(void* const* d_in, const int* in_sizes, int n_in,
                              void* d_out, int out_size, void* d_ws, size_t ws_size,
                              hipStream_t stream) {
    const float* sat = (const float*)d_in[0];
    const float* grd = (const float*)d_in[1];
    float* out = (float*)d_out;

    const bool useWs = (ws_size >= (size_t)2 * 1024 * 1024);
    f16* gHi;
    f16* gLo;
    if (useWs) {
        gHi = (f16*)d_ws;
        gLo = gHi + 524288;
    } else {
        gHi = (f16*)out;                 // floats [0, 262144)
        gLo = (f16*)(out + 262144);      // floats [262144, 524288)
    }

    prep_k<<<64, 256, 0, stream>>>(grd, gHi, gLo);
    corr_k<<<256, 1024, 0, stream>>>(sat, gHi, gLo, out,
                                     (const float4*)sat, (const float4*)grd,
                                     useWs ? 1 : 0);
    if (!useWs)
        copy_k<<<512, 256, 0, stream>>>((const float4*)sat, (const float4*)grd, (float4*)out);
}